// Round 1
// baseline (3005.399 us; speedup 1.0000x reference)
//
#include <hip/hip_runtime.h>
#include <cstdint>
#include <cstddef>

// GotenNet block, fp32. Sizes fixed by the reference.
#define NND 100000
#define E1N 200000
#define E2N 400000
#define DIM 128
#define NH  8
#define DH  16

typedef float fx4 __attribute__((ext_vector_type(4)));

static __device__ __forceinline__ int f2oi(float f) {
    int i = __float_as_int(f);
    return i >= 0 ? i : (i ^ 0x7fffffff);
}
static __device__ __forceinline__ float oi2f(int i) {
    return __int_as_float(i >= 0 ? i : (i ^ 0x7fffffff));
}

// ---------------------------------------------------------------------------
// init: softmax stats (gmax as ordered-int, gsum)
__global__ __launch_bounds__(64) void k_init(int* gmax, float* gsum) {
    int t = threadIdx.x;
    if (t < NH) gmax[t] = (int)0x80000000;
    if (t >= NH && t < 2 * NH) gsum[t - NH] = 0.0f;
}

// ---------------------------------------------------------------------------
// QKV node projections: Hq/Hk/Hv = h @ W{q,k,v} + b   [100000,128]x[128,128]
__global__ __launch_bounds__(256) void k_proj(
    const float* __restrict__ h,
    const float* __restrict__ Wq, const float* __restrict__ bq,
    const float* __restrict__ Wk, const float* __restrict__ bk,
    const float* __restrict__ Wv, const float* __restrict__ bv,
    float* __restrict__ Hq, float* __restrict__ Hk, float* __restrict__ Hv)
{
    __shared__ __align__(16) float xs[32 * 132];
    const int t = threadIdx.x;
    const size_t r0 = (size_t)blockIdx.x * 32;   // grid = 3125, exact

#pragma unroll
    for (int i = 0; i < 4; ++i) {
        int idx = t + i * 256;
        int row = idx >> 5, c4 = idx & 31;
        *reinterpret_cast<fx4*>(&xs[row * 132 + c4 * 4]) =
            *reinterpret_cast<const fx4*>(&h[(r0 + row) * DIM + c4 * 4]);
    }
    __syncthreads();

    const int cg = t & 31, rg = t >> 5;   // 32 col-groups x 8 row-groups
    const float* const Ws[3] = {Wq, Wk, Wv};
    const float* const bs[3] = {bq, bk, bv};
    float* const Os[3] = {Hq, Hk, Hv};

#pragma unroll
    for (int m = 0; m < 3; ++m) {
        const float* __restrict__ W = Ws[m];
        float acc[4][4];
#pragma unroll
        for (int r = 0; r < 4; ++r)
#pragma unroll
            for (int c = 0; c < 4; ++c) acc[r][c] = 0.0f;

        for (int k = 0; k < DIM; k += 4) {
            fx4 xr[4];
#pragma unroll
            for (int r = 0; r < 4; ++r)
                xr[r] = *reinterpret_cast<const fx4*>(&xs[(rg * 4 + r) * 132 + k]);
#pragma unroll
            for (int kk = 0; kk < 4; ++kk) {
                fx4 w = *reinterpret_cast<const fx4*>(&W[(size_t)(k + kk) * DIM + cg * 4]);
#pragma unroll
                for (int r = 0; r < 4; ++r)
#pragma unroll
                    for (int c = 0; c < 4; ++c)
                        acc[r][c] = fmaf(xr[r][kk], w[c], acc[r][c]);
            }
        }
        const float* __restrict__ b = bs[m];
        float* __restrict__ O = Os[m];
#pragma unroll
        for (int r = 0; r < 4; ++r) {
            fx4 o;
#pragma unroll
            for (int c = 0; c < 4; ++c) o[c] = acc[r][c] + b[cg * 4 + c];
            *reinterpret_cast<fx4*>(&O[(r0 + rg * 4 + r) * DIM + cg * 4]) = o;
        }
    }
}

// ---------------------------------------------------------------------------
// logits[e,h] = (q.k)/4 + t_e2 @ Wg + bg ; global per-head max via ordered-int
__global__ __launch_bounds__(256) void k_logits(
    const float* __restrict__ Hq, const float* __restrict__ Hk,
    const float* __restrict__ t_e2,
    const float* __restrict__ Wg, const float* __restrict__ bg,
    const int* __restrict__ ei2,
    float* __restrict__ P, int* __restrict__ gmax)
{
    __shared__ float wgT[NH * 132];   // Wg transposed [h][k]
    __shared__ int lmax[NH];
    const int t = threadIdx.x;
#pragma unroll
    for (int i = 0; i < 4; ++i) {
        int idx = t + i * 256;        // 1024 = 128*8
        wgT[(idx & 7) * 132 + (idx >> 3)] = Wg[idx];
    }
    if (t < NH) lmax[t] = (int)0x80000000;
    __syncthreads();

    const int idx = blockIdx.x * 256 + t;   // grid = 12500, exact E2*H
    const int e = idx >> 3, hh = idx & 7;
    const int s = ei2[e], d = ei2[E2N + e];

    const float* __restrict__ q  = &Hq[(size_t)d * DIM + hh * DH];
    const float* __restrict__ kp = &Hk[(size_t)s * DIM + hh * DH];
    float dot = 0.0f;
#pragma unroll
    for (int j = 0; j < DH; j += 4) {
        fx4 qa = *reinterpret_cast<const fx4*>(&q[j]);
        fx4 ka = *reinterpret_cast<const fx4*>(&kp[j]);
        dot += qa[0] * ka[0] + qa[1] * ka[1] + qa[2] * ka[2] + qa[3] * ka[3];
    }
    float g = bg[hh];
    const float* __restrict__ te = &t_e2[(size_t)e * DIM];
    const float* __restrict__ wr = &wgT[hh * 132];
#pragma unroll
    for (int k = 0; k < DIM; k += 4) {
        fx4 tv = *reinterpret_cast<const fx4*>(&te[k]);
        fx4 wv = *reinterpret_cast<const fx4*>(&wr[k]);
        g += tv[0] * wv[0] + tv[1] * wv[1] + tv[2] * wv[2] + tv[3] * wv[3];
    }
    float logit = dot * 0.25f + g;   // 1/sqrt(16)
    P[idx] = logit;

    float m = logit;
#pragma unroll
    for (int off = 8; off < 64; off <<= 1)
        m = fmaxf(m, __shfl_xor(m, off));
    if ((t & 63) < NH) atomicMax(&lmax[hh], f2oi(m));
    __syncthreads();
    if (t < NH) atomicMax(&gmax[t], lmax[t]);
}

// ---------------------------------------------------------------------------
// P <- exp(P - max[h]); gsum[h] += sum
__global__ __launch_bounds__(256) void k_sumexp(
    float* __restrict__ P, const int* __restrict__ gmax, float* __restrict__ gsum)
{
    __shared__ float lsum[NH];
    __shared__ float mx[NH];
    const int t = threadIdx.x;
    if (t < NH) { lsum[t] = 0.0f; mx[t] = oi2f(gmax[t]); }
    __syncthreads();
    const int idx = blockIdx.x * 256 + t;   // grid = 12500
    const int hh = idx & 7;
    float p = expf(P[idx] - mx[hh]);
    P[idx] = p;
#pragma unroll
    for (int off = 8; off < 64; off <<= 1) p += __shfl_xor(p, off);
    if ((t & 63) < NH) atomicAdd(&lsum[hh], p);
    __syncthreads();
    if (t < NH) atomicAdd(&gsum[t], lsum[t]);
}

// ---------------------------------------------------------------------------
// h_update[dst] += alpha * v   (one wave per edge, 2 elems/lane)
__global__ __launch_bounds__(256) void k_scatter(
    const float* __restrict__ P, const float* __restrict__ gsum,
    const float* __restrict__ Hv, const int* __restrict__ ei2,
    float* __restrict__ h_update)
{
    __shared__ float inv[NH];
    const int t = threadIdx.x;
    if (t < NH) inv[t] = 1.0f / gsum[t];
    __syncthreads();
    const int lane = t & 63;
    const int wave = (blockIdx.x * 256 + t) >> 6;
    const int nw = gridDim.x * 4;
    const int hh = lane >> 3;            // head of elems {2*lane, 2*lane+1}
    const float iv = inv[hh];
    for (int e = wave; e < E2N; e += nw) {
        const int s = ei2[e], d = ei2[E2N + e];
        const float a = P[e * NH + hh] * iv;
        const float2 v = *reinterpret_cast<const float2*>(&Hv[(size_t)s * DIM + lane * 2]);
        float* dst = &h_update[(size_t)d * DIM + lane * 2];
        atomicAdd(dst, a * v.x);
        atomicAdd(dst + 1, a * v.y);
    }
}

// ---------------------------------------------------------------------------
// h_out = h + h_update @ Wo + bo
__global__ __launch_bounds__(256) void k_hout(
    const float* __restrict__ hu, const float* __restrict__ h,
    const float* __restrict__ Wo, const float* __restrict__ bo,
    float* __restrict__ hout)
{
    __shared__ __align__(16) float xs[32 * 132];
    const int t = threadIdx.x;
    const size_t r0 = (size_t)blockIdx.x * 32;
#pragma unroll
    for (int i = 0; i < 4; ++i) {
        int idx = t + i * 256;
        int row = idx >> 5, c4 = idx & 31;
        *reinterpret_cast<fx4*>(&xs[row * 132 + c4 * 4]) =
            *reinterpret_cast<const fx4*>(&hu[(r0 + row) * DIM + c4 * 4]);
    }
    __syncthreads();
    const int cg = t & 31, rg = t >> 5;
    float acc[4][4];
#pragma unroll
    for (int r = 0; r < 4; ++r)
#pragma unroll
        for (int c = 0; c < 4; ++c) acc[r][c] = 0.0f;

    for (int k = 0; k < DIM; k += 4) {
        fx4 xr[4];
#pragma unroll
        for (int r = 0; r < 4; ++r)
            xr[r] = *reinterpret_cast<const fx4*>(&xs[(rg * 4 + r) * 132 + k]);
#pragma unroll
        for (int kk = 0; kk < 4; ++kk) {
            fx4 w = *reinterpret_cast<const fx4*>(&Wo[(size_t)(k + kk) * DIM + cg * 4]);
#pragma unroll
            for (int r = 0; r < 4; ++r)
#pragma unroll
                for (int c = 0; c < 4; ++c)
                    acc[r][c] = fmaf(xr[r][kk], w[c], acc[r][c]);
        }
    }
#pragma unroll
    for (int r = 0; r < 4; ++r) {
        fx4 res = *reinterpret_cast<const fx4*>(&h[(r0 + rg * 4 + r) * DIM + cg * 4]);
        fx4 o;
#pragma unroll
        for (int c = 0; c < 4; ++c) o[c] = acc[r][c] + bo[cg * 4 + c] + res[c];
        *reinterpret_cast<fx4*>(&hout[(r0 + rg * 4 + r) * DIM + cg * 4]) = o;
    }
}

// ---------------------------------------------------------------------------
// Edge MLP: out[rr] = resid + silu(concat(hn[s],hn[d],resid) @ W1 + b1) @ W2 + b2
// HTR=false: GATA update over E2 (rr = e, resid from original t_e2, write t_out)
// HTR=true : EdgeHTR over E1 (rr = e1map[e], resid/out in-place on t region)
template<bool HTR>
__global__ __launch_bounds__(256) void k_edge_mlp(
    const float* __restrict__ hn,
    const float* __restrict__ t_resid,
    const int* __restrict__ ei, int esecond,
    const int* __restrict__ e1map,
    const float* __restrict__ W1, const float* __restrict__ b1,
    const float* __restrict__ W2, const float* __restrict__ b2,
    float* __restrict__ t_out)
{
    __shared__ __align__(16) float smem[32 * 388];   // x tile; later aliased as hmid [32][132]
    const int t = threadIdx.x;
    const int e0 = blockIdx.x * 32;

#pragma unroll
    for (int i = 0; i < 12; ++i) {
        int idx = t + i * 256;           // 3072 float4 slots = 32 rows * 96
        int row = idx / 96;
        int c4 = idx - row * 96;
        int e = e0 + row;
        int seg = c4 >> 5;
        int cc = (c4 & 31) * 4;
        const float* sp;
        if (seg == 0)      sp = &hn[(size_t)ei[e] * DIM + cc];
        else if (seg == 1) sp = &hn[(size_t)ei[esecond + e] * DIM + cc];
        else {
            size_t rr = HTR ? (size_t)e1map[e] : (size_t)e;
            sp = &t_resid[rr * DIM + cc];
        }
        *reinterpret_cast<fx4*>(&smem[row * 388 + seg * DIM + cc]) =
            *reinterpret_cast<const fx4*>(sp);
    }
    __syncthreads();

    const int cg = t & 31, rg = t >> 5;
    float acc[4][4];
#pragma unroll
    for (int r = 0; r < 4; ++r)
#pragma unroll
        for (int c = 0; c < 4; ++c) acc[r][c] = 0.0f;

    for (int k = 0; k < 3 * DIM; k += 4) {
        fx4 xr[4];
#pragma unroll
        for (int r = 0; r < 4; ++r)
            xr[r] = *reinterpret_cast<const fx4*>(&smem[(rg * 4 + r) * 388 + k]);
#pragma unroll
        for (int kk = 0; kk < 4; ++kk) {
            fx4 w = *reinterpret_cast<const fx4*>(&W1[(size_t)(k + kk) * DIM + cg * 4]);
#pragma unroll
            for (int r = 0; r < 4; ++r)
#pragma unroll
                for (int c = 0; c < 4; ++c)
                    acc[r][c] = fmaf(xr[r][kk], w[c], acc[r][c]);
        }
    }
    __syncthreads();   // all xs reads done -> safe to alias hmid into smem

#pragma unroll
    for (int r = 0; r < 4; ++r) {
        fx4 o;
#pragma unroll
        for (int c = 0; c < 4; ++c) {
            float x = acc[r][c] + b1[cg * 4 + c];
            o[c] = x / (1.0f + expf(-x));   // silu
        }
        *reinterpret_cast<fx4*>(&smem[(rg * 4 + r) * 132 + cg * 4]) = o;
    }
    __syncthreads();

    float acc2[4][4];
#pragma unroll
    for (int r = 0; r < 4; ++r)
#pragma unroll
        for (int c = 0; c < 4; ++c) acc2[r][c] = 0.0f;

    for (int k = 0; k < DIM; k += 4) {
        fx4 xr[4];
#pragma unroll
        for (int r = 0; r < 4; ++r)
            xr[r] = *reinterpret_cast<const fx4*>(&smem[(rg * 4 + r) * 132 + k]);
#pragma unroll
        for (int kk = 0; kk < 4; ++kk) {
            fx4 w = *reinterpret_cast<const fx4*>(&W2[(size_t)(k + kk) * DIM + cg * 4]);
#pragma unroll
            for (int r = 0; r < 4; ++r)
#pragma unroll
                for (int c = 0; c < 4; ++c)
                    acc2[r][c] = fmaf(xr[r][kk], w[c], acc2[r][c]);
        }
    }
#pragma unroll
    for (int r = 0; r < 4; ++r) {
        int e = e0 + rg * 4 + r;
        size_t rr = HTR ? (size_t)e1map[e] : (size_t)e;
        fx4 res = *reinterpret_cast<const fx4*>(&t_resid[rr * DIM + cg * 4]);
        fx4 o;
#pragma unroll
        for (int c = 0; c < 4; ++c) o[c] = acc2[r][c] + b2[cg * 4 + c] + res[c];
        *reinterpret_cast<fx4*>(&t_out[rr * DIM + cg * 4]) = o;
    }
}

// ---------------------------------------------------------------------------
// EQFF in-place: h = h + silu(h@Wf1+bf1)@Wf2+bf2   (D -> 2D -> D)
__global__ __launch_bounds__(256) void k_eqff(
    const float* __restrict__ Wf1, const float* __restrict__ bf1,
    const float* __restrict__ Wf2, const float* __restrict__ bf2,
    float* __restrict__ h_io)
{
    __shared__ __align__(16) float xs[32 * 132];
    __shared__ __align__(16) float mid[32 * 260];
    const int t = threadIdx.x;
    const size_t r0 = (size_t)blockIdx.x * 32;
#pragma unroll
    for (int i = 0; i < 4; ++i) {
        int idx = t + i * 256;
        int row = idx >> 5, c4 = idx & 31;
        *reinterpret_cast<fx4*>(&xs[row * 132 + c4 * 4]) =
            *reinterpret_cast<const fx4*>(&h_io[(r0 + row) * DIM + c4 * 4]);
    }
    __syncthreads();
    const int cg = t & 31, rg = t >> 5;

#pragma unroll
    for (int pass = 0; pass < 2; ++pass) {
        float acc[4][4];
#pragma unroll
        for (int r = 0; r < 4; ++r)
#pragma unroll
            for (int c = 0; c < 4; ++c) acc[r][c] = 0.0f;

        for (int k = 0; k < DIM; k += 4) {
            fx4 xr[4];
#pragma unroll
            for (int r = 0; r < 4; ++r)
                xr[r] = *reinterpret_cast<const fx4*>(&xs[(rg * 4 + r) * 132 + k]);
#pragma unroll
            for (int kk = 0; kk < 4; ++kk) {
                fx4 w = *reinterpret_cast<const fx4*>(&Wf1[(size_t)(k + kk) * 256 + pass * DIM + cg * 4]);
#pragma unroll
                for (int r = 0; r < 4; ++r)
#pragma unroll
                    for (int c = 0; c < 4; ++c)
                        acc[r][c] = fmaf(xr[r][kk], w[c], acc[r][c]);
            }
        }
#pragma unroll
        for (int r = 0; r < 4; ++r) {
            fx4 o;
#pragma unroll
            for (int c = 0; c < 4; ++c) {
                float x = acc[r][c] + bf1[pass * DIM + cg * 4 + c];
                o[c] = x / (1.0f + expf(-x));
            }
            *reinterpret_cast<fx4*>(&mid[(rg * 4 + r) * 260 + pass * DIM + cg * 4]) = o;
        }
    }
    __syncthreads();

    float acc2[4][4];
#pragma unroll
    for (int r = 0; r < 4; ++r)
#pragma unroll
        for (int c = 0; c < 4; ++c) acc2[r][c] = 0.0f;

    for (int k = 0; k < 256; k += 4) {
        fx4 xr[4];
#pragma unroll
        for (int r = 0; r < 4; ++r)
            xr[r] = *reinterpret_cast<const fx4*>(&mid[(rg * 4 + r) * 260 + k]);
#pragma unroll
        for (int kk = 0; kk < 4; ++kk) {
            fx4 w = *reinterpret_cast<const fx4*>(&Wf2[(size_t)(k + kk) * DIM + cg * 4]);
#pragma unroll
            for (int r = 0; r < 4; ++r)
#pragma unroll
                for (int c = 0; c < 4; ++c)
                    acc2[r][c] = fmaf(xr[r][kk], w[c], acc2[r][c]);
        }
    }
#pragma unroll
    for (int r = 0; r < 4; ++r) {
        fx4 res = *reinterpret_cast<const fx4*>(&xs[(rg * 4 + r) * 132 + cg * 4]);
        fx4 o;
#pragma unroll
        for (int c = 0; c < 4; ++c) o[c] = acc2[r][c] + bf2[cg * 4 + c] + res[c];
        *reinterpret_cast<fx4*>(&h_io[(r0 + rg * 4 + r) * DIM + cg * 4]) = o;
    }
}

// ---------------------------------------------------------------------------
extern "C" void kernel_launch(void* const* d_in, const int* in_sizes, int n_in,
                              void* d_out, int out_size, void* d_ws, size_t ws_size,
                              hipStream_t stream)
{
    (void)in_sizes; (void)n_in; (void)out_size; (void)ws_size;

    const float* h    = (const float*)d_in[0];
    const float* t_e2 = (const float*)d_in[1];
    const int* ei1    = (const int*)d_in[2];
    const int* ei2    = (const int*)d_in[3];
    const int* e1map  = (const int*)d_in[4];
    const float* Wq = (const float*)d_in[5];  const float* bq = (const float*)d_in[6];
    const float* Wk = (const float*)d_in[7];  const float* bk = (const float*)d_in[8];
    const float* Wv = (const float*)d_in[9];  const float* bv = (const float*)d_in[10];
    const float* Wg = (const float*)d_in[11]; const float* bg = (const float*)d_in[12];
    const float* Wo = (const float*)d_in[13]; const float* bo = (const float*)d_in[14];
    const float* We1= (const float*)d_in[15]; const float* be1= (const float*)d_in[16];
    const float* We2= (const float*)d_in[17]; const float* be2= (const float*)d_in[18];
    const float* Wh1= (const float*)d_in[19]; const float* bh1= (const float*)d_in[20];
    const float* Wh2= (const float*)d_in[21]; const float* bh2= (const float*)d_in[22];
    const float* Wf1= (const float*)d_in[23]; const float* bf1= (const float*)d_in[24];
    const float* Wf2= (const float*)d_in[25]; const float* bf2= (const float*)d_in[26];

    // workspace layout (floats): Hq | Hk | Hv | h_update | P | stats
    const size_t nd = (size_t)NND * DIM;          // 12.8M
    float* ws   = (float*)d_ws;
    float* Hq   = ws;
    float* Hk   = Hq + nd;
    float* Hv   = Hk + nd;
    float* hu   = Hv + nd;
    float* P    = hu + nd;
    int*   gmax = (int*)(P + (size_t)E2N * NH);
    float* gsum = (float*)(gmax + NH);

    float* h_out = (float*)d_out;                  // [N, D]
    float* t_out = h_out + nd;                     // [E2, D]

    hipMemsetAsync(hu, 0, nd * sizeof(float), stream);
    k_init<<<1, 64, 0, stream>>>(gmax, gsum);

    k_proj<<<NND / 32, 256, 0, stream>>>(h, Wq, bq, Wk, bk, Wv, bv, Hq, Hk, Hv);
    k_logits<<<(E2N * NH) / 256, 256, 0, stream>>>(Hq, Hk, t_e2, Wg, bg, ei2, P, gmax);
    k_sumexp<<<(E2N * NH) / 256, 256, 0, stream>>>(P, gmax, gsum);
    k_scatter<<<4096, 256, 0, stream>>>(P, gsum, Hv, ei2, hu);
    k_hout<<<NND / 32, 256, 0, stream>>>(hu, h, Wo, bo, h_out);

    // GATA edge update: reads h_out + original t_e2, writes t_out (all E2 rows)
    k_edge_mlp<false><<<E2N / 32, 256, 0, stream>>>(
        h_out, t_e2, ei2, E2N, nullptr, We1, be1, We2, be2, t_out);
    // EdgeHTR: in-place on t_out rows e1map[e] (bijection: e1_to_e2 = arange)
    k_edge_mlp<true><<<E1N / 32, 256, 0, stream>>>(
        h_out, t_out, ei1, E1N, e1map, Wh1, bh1, Wh2, bh2, t_out);
    // EQFF: in-place on h_out
    k_eqff<<<NND / 32, 256, 0, stream>>>(Wf1, bf1, Wf2, bf2, h_out);
}

// Round 2
// 2302.135 us; speedup vs baseline: 1.3055x; 1.3055x over previous
//
#include <hip/hip_runtime.h>
#include <cstdint>
#include <cstddef>

// GotenNet block. GEMM-shaped compute on bf16 MFMA, gather/softmax/scatter fp32.
#define NND 100000
#define E1N 200000
#define E2N 400000
#define DIM 128
#define NH  8
#define DH  16

typedef float fx4 __attribute__((ext_vector_type(4)));
typedef float f32x4 __attribute__((ext_vector_type(4)));
typedef short bf16x8 __attribute__((ext_vector_type(8)));   // 8 bf16 in 4 VGPRs
typedef unsigned short u16;
typedef unsigned short us4 __attribute__((ext_vector_type(4)));

static __device__ __forceinline__ int f2oi(float f) {
    int i = __float_as_int(f);
    return i >= 0 ? i : (i ^ 0x7fffffff);
}
static __device__ __forceinline__ float oi2f(int i) {
    return __int_as_float(i >= 0 ? i : (i ^ 0x7fffffff));
}
// fp32 -> bf16, round-to-nearest-even
static __device__ __forceinline__ u16 f2b(float f) {
    unsigned u = __float_as_uint(f);
    u = (u + 0x7fffu + ((u >> 16) & 1u)) >> 16;
    return (u16)u;
}

#define MFMA16(a, b, c) __builtin_amdgcn_mfma_f32_16x16x32_bf16((a), (b), (c), 0, 0, 0)
#define ZACC4(acc) do { _Pragma("unroll") for (int _f = 0; _f < 4; ++_f) \
    acc[_f] = (f32x4){0.f, 0.f, 0.f, 0.f}; } while (0)

// ---------------------------------------------------------------------------
__global__ __launch_bounds__(64) void k_init(int* gmax, float* gsum) {
    int t = threadIdx.x;
    if (t < NH) gmax[t] = (int)0x80000000;
    if (t >= NH && t < 2 * NH) gsum[t - NH] = 0.0f;
}

// ---------------------------------------------------------------------------
// weight prep: WT[n][k] = bf16(W[k][n])
__global__ __launch_bounds__(256) void k_wprep(
    const float* __restrict__ W, u16* __restrict__ WT, int K, int N)
{
    int idx = blockIdx.x * 256 + threadIdx.x;
    if (idx >= K * N) return;
    int n = idx / K, k = idx - n * K;
    WT[idx] = f2b(W[(size_t)k * N + n]);
}

// ---------------------------------------------------------------------------
// QKV projections via MFMA: Hq/Hk/Hv = h @ W{q,k,v} + b   (fp32 out)
__global__ __launch_bounds__(256) void k_proj(
    const float* __restrict__ h,
    const u16* __restrict__ WqT, const float* __restrict__ bq,
    const u16* __restrict__ WkT, const float* __restrict__ bk,
    const u16* __restrict__ WvT, const float* __restrict__ bv,
    float* __restrict__ Hq, float* __restrict__ Hk, float* __restrict__ Hv)
{
    __shared__ __align__(16) u16 xs[32 * 136];
    const int t = threadIdx.x;
    const size_t r0 = (size_t)blockIdx.x * 32;
#pragma unroll
    for (int i = 0; i < 4; ++i) {
        int idx = t + i * 256;
        int row = idx >> 5, c4 = (idx & 31) * 4;
        fx4 v = *reinterpret_cast<const fx4*>(&h[(r0 + row) * DIM + c4]);
        us4 b; b[0] = f2b(v[0]); b[1] = f2b(v[1]); b[2] = f2b(v[2]); b[3] = f2b(v[3]);
        *reinterpret_cast<us4*>(&xs[row * 136 + c4]) = b;
    }
    __syncthreads();
    const int lane = t & 63, w = t >> 6;
    const int wr = w & 1, wc = w >> 1;
    const int l16 = lane & 15, lg = lane >> 4;
    const int arow = wr * 16 + l16;
    bf16x8 a[4];
#pragma unroll
    for (int kt = 0; kt < 4; ++kt)
        a[kt] = *reinterpret_cast<const bf16x8*>(&xs[arow * 136 + kt * 32 + lg * 8]);

    const u16* const Ws[3] = {WqT, WkT, WvT};
    const float* const bs[3] = {bq, bk, bv};
    float* const Os[3] = {Hq, Hk, Hv};
#pragma unroll
    for (int m = 0; m < 3; ++m) {
        f32x4 acc[4]; ZACC4(acc);
#pragma unroll
        for (int f = 0; f < 4; ++f) {
            const int col = wc * 64 + f * 16 + l16;
#pragma unroll
            for (int kt = 0; kt < 4; ++kt) {
                bf16x8 b = *reinterpret_cast<const bf16x8*>(
                    &Ws[m][(size_t)col * DIM + kt * 32 + lg * 8]);
                acc[f] = MFMA16(a[kt], b, acc[f]);
            }
        }
#pragma unroll
        for (int f = 0; f < 4; ++f) {
            const int col = wc * 64 + f * 16 + l16;
            const float bb = bs[m][col];
#pragma unroll
            for (int r = 0; r < 4; ++r) {
                const int row = wr * 16 + lg * 4 + r;
                Os[m][(r0 + row) * DIM + col] = acc[f][r] + bb;
            }
        }
    }
}

// ---------------------------------------------------------------------------
// logits[e,h] = (q.k)/4 + t_e2 @ Wg + bg ; global per-head max (fp32, unchanged)
__global__ __launch_bounds__(256) void k_logits(
    const float* __restrict__ Hq, const float* __restrict__ Hk,
    const float* __restrict__ t_e2,
    const float* __restrict__ Wg, const float* __restrict__ bg,
    const int* __restrict__ ei2,
    float* __restrict__ P, int* __restrict__ gmax)
{
    __shared__ float wgT[NH * 132];
    __shared__ int lmax[NH];
    const int t = threadIdx.x;
#pragma unroll
    for (int i = 0; i < 4; ++i) {
        int idx = t + i * 256;
        wgT[(idx & 7) * 132 + (idx >> 3)] = Wg[idx];
    }
    if (t < NH) lmax[t] = (int)0x80000000;
    __syncthreads();

    const int idx = blockIdx.x * 256 + t;
    const int e = idx >> 3, hh = idx & 7;
    const int s = ei2[e], d = ei2[E2N + e];

    const float* __restrict__ q  = &Hq[(size_t)d * DIM + hh * DH];
    const float* __restrict__ kp = &Hk[(size_t)s * DIM + hh * DH];
    float dot = 0.0f;
#pragma unroll
    for (int j = 0; j < DH; j += 4) {
        fx4 qa = *reinterpret_cast<const fx4*>(&q[j]);
        fx4 ka = *reinterpret_cast<const fx4*>(&kp[j]);
        dot += qa[0] * ka[0] + qa[1] * ka[1] + qa[2] * ka[2] + qa[3] * ka[3];
    }
    float g = bg[hh];
    const float* __restrict__ te = &t_e2[(size_t)e * DIM];
    const float* __restrict__ wr = &wgT[hh * 132];
#pragma unroll
    for (int k = 0; k < DIM; k += 4) {
        fx4 tv = *reinterpret_cast<const fx4*>(&te[k]);
        fx4 wv = *reinterpret_cast<const fx4*>(&wr[k]);
        g += tv[0] * wv[0] + tv[1] * wv[1] + tv[2] * wv[2] + tv[3] * wv[3];
    }
    float logit = dot * 0.25f + g;
    P[idx] = logit;

    float m = logit;
#pragma unroll
    for (int off = 8; off < 64; off <<= 1)
        m = fmaxf(m, __shfl_xor(m, off));
    if ((t & 63) < NH) atomicMax(&lmax[hh], f2oi(m));
    __syncthreads();
    if (t < NH) atomicMax(&gmax[t], lmax[t]);
}

// ---------------------------------------------------------------------------
__global__ __launch_bounds__(256) void k_sumexp(
    float* __restrict__ P, const int* __restrict__ gmax, float* __restrict__ gsum)
{
    __shared__ float lsum[NH];
    __shared__ float mx[NH];
    const int t = threadIdx.x;
    if (t < NH) { lsum[t] = 0.0f; mx[t] = oi2f(gmax[t]); }
    __syncthreads();
    const int idx = blockIdx.x * 256 + t;
    const int hh = idx & 7;
    float p = expf(P[idx] - mx[hh]);
    P[idx] = p;
#pragma unroll
    for (int off = 8; off < 64; off <<= 1) p += __shfl_xor(p, off);
    if ((t & 63) < NH) atomicAdd(&lsum[hh], p);
    __syncthreads();
    if (t < NH) atomicAdd(&gsum[t], lsum[t]);
}

// ---------------------------------------------------------------------------
__global__ __launch_bounds__(256) void k_scatter(
    const float* __restrict__ P, const float* __restrict__ gsum,
    const float* __restrict__ Hv, const int* __restrict__ ei2,
    float* __restrict__ h_update)
{
    __shared__ float inv[NH];
    const int t = threadIdx.x;
    if (t < NH) inv[t] = 1.0f / gsum[t];
    __syncthreads();
    const int lane = t & 63;
    const int wave = (blockIdx.x * 256 + t) >> 6;
    const int nw = gridDim.x * 4;
    const int hh = lane >> 3;
    const float iv = inv[hh];
    for (int e = wave; e < E2N; e += nw) {
        const int s = ei2[e], d = ei2[E2N + e];
        const float a = P[e * NH + hh] * iv;
        const float2 v = *reinterpret_cast<const float2*>(&Hv[(size_t)s * DIM + lane * 2]);
        float* dst = &h_update[(size_t)d * DIM + lane * 2];
        atomicAdd(dst, a * v.x);
        atomicAdd(dst + 1, a * v.y);
    }
}

// ---------------------------------------------------------------------------
// h2 = h + hu @ Wo + bo  (MFMA). Writes fp32 h2 AND bf16 shadow h2b.
__global__ __launch_bounds__(256) void k_hout(
    const float* __restrict__ hu, const float* __restrict__ h,
    const u16* __restrict__ WoT, const float* __restrict__ bo,
    float* __restrict__ h2, u16* __restrict__ h2b)
{
    __shared__ __align__(16) u16 xs[32 * 136];
    const int t = threadIdx.x;
    const size_t r0 = (size_t)blockIdx.x * 32;
#pragma unroll
    for (int i = 0; i < 4; ++i) {
        int idx = t + i * 256;
        int row = idx >> 5, c4 = (idx & 31) * 4;
        fx4 v = *reinterpret_cast<const fx4*>(&hu[(r0 + row) * DIM + c4]);
        us4 b; b[0] = f2b(v[0]); b[1] = f2b(v[1]); b[2] = f2b(v[2]); b[3] = f2b(v[3]);
        *reinterpret_cast<us4*>(&xs[row * 136 + c4]) = b;
    }
    __syncthreads();
    const int lane = t & 63, w = t >> 6;
    const int wr = w & 1, wc = w >> 1;
    const int l16 = lane & 15, lg = lane >> 4;
    const int arow = wr * 16 + l16;

    f32x4 acc[4]; ZACC4(acc);
#pragma unroll
    for (int kt = 0; kt < 4; ++kt) {
        bf16x8 a = *reinterpret_cast<const bf16x8*>(&xs[arow * 136 + kt * 32 + lg * 8]);
#pragma unroll
        for (int f = 0; f < 4; ++f) {
            const int col = wc * 64 + f * 16 + l16;
            bf16x8 b = *reinterpret_cast<const bf16x8*>(
                &WoT[(size_t)col * DIM + kt * 32 + lg * 8]);
            acc[f] = MFMA16(a, b, acc[f]);
        }
    }
#pragma unroll
    for (int f = 0; f < 4; ++f) {
        const int col = wc * 64 + f * 16 + l16;
        const float bb = bo[col];
#pragma unroll
        for (int r = 0; r < 4; ++r) {
            const size_t row = r0 + wr * 16 + lg * 4 + r;
            float o = acc[f][r] + bb + h[row * DIM + col];
            h2[row * DIM + col] = o;
            h2b[row * DIM + col] = f2b(o);
        }
    }
}

// ---------------------------------------------------------------------------
// Edge MLP via MFMA: out[rr] = resid + silu(concat(h2[s],h2[d],resid)@W1+b1)@W2+b2
// t_resid/t_out may alias (HTR) -> no restrict on them.
template<bool HTR>
__global__ __launch_bounds__(256) void k_edge_mlp(
    const u16* __restrict__ hb,
    const float* t_resid,
    const int* __restrict__ ei, int esecond,
    const int* __restrict__ e1map,
    const u16* __restrict__ W1T, const float* __restrict__ b1,
    const u16* __restrict__ W2T, const float* __restrict__ b2,
    float* t_out)
{
    __shared__ __align__(16) u16 xs[32 * 392];   // [32][384] pad->392 (2-way free)
    __shared__ __align__(16) u16 hs[32 * 136];
    const int t = threadIdx.x;
    const int e0 = blockIdx.x * 32;

#pragma unroll
    for (int i = 0; i < 12; ++i) {
        int idx = t + i * 256;               // 3072 = 32 rows * 96 4-elem chunks
        int row = idx / 96;
        int c4 = idx - row * 96;
        int seg = c4 >> 5;
        int cc = (c4 & 31) * 4;
        int e = e0 + row;
        us4 bv;
        if (seg == 2) {
            size_t rr = HTR ? (size_t)e1map[e] : (size_t)e;
            fx4 v = *reinterpret_cast<const fx4*>(&t_resid[rr * DIM + cc]);
            bv[0] = f2b(v[0]); bv[1] = f2b(v[1]); bv[2] = f2b(v[2]); bv[3] = f2b(v[3]);
        } else {
            int node = ei[(seg ? esecond : 0) + e];
            bv = *reinterpret_cast<const us4*>(&hb[(size_t)node * DIM + cc]);
        }
        *reinterpret_cast<us4*>(&xs[row * 392 + seg * DIM + cc]) = bv;
    }
    __syncthreads();
    const int lane = t & 63, w = t >> 6;
    const int wr = w & 1, wc = w >> 1;
    const int l16 = lane & 15, lg = lane >> 4;
    const int arow = wr * 16 + l16;

    f32x4 acc[4]; ZACC4(acc);
    for (int kt = 0; kt < 12; ++kt) {
        bf16x8 a = *reinterpret_cast<const bf16x8*>(&xs[arow * 392 + kt * 32 + lg * 8]);
#pragma unroll
        for (int f = 0; f < 4; ++f) {
            const int col = wc * 64 + f * 16 + l16;
            bf16x8 b = *reinterpret_cast<const bf16x8*>(
                &W1T[(size_t)col * 384 + kt * 32 + lg * 8]);
            acc[f] = MFMA16(a, b, acc[f]);
        }
    }
#pragma unroll
    for (int f = 0; f < 4; ++f) {
        const int col = wc * 64 + f * 16 + l16;
        const float bb = b1[col];
#pragma unroll
        for (int r = 0; r < 4; ++r) {
            float x = acc[f][r] + bb;
            x = x / (1.0f + __expf(-x));     // silu
            hs[(wr * 16 + lg * 4 + r) * 136 + col] = f2b(x);
        }
    }
    __syncthreads();

    f32x4 acc2[4]; ZACC4(acc2);
#pragma unroll
    for (int kt = 0; kt < 4; ++kt) {
        bf16x8 a = *reinterpret_cast<const bf16x8*>(&hs[arow * 136 + kt * 32 + lg * 8]);
#pragma unroll
        for (int f = 0; f < 4; ++f) {
            const int col = wc * 64 + f * 16 + l16;
            bf16x8 b = *reinterpret_cast<const bf16x8*>(
                &W2T[(size_t)col * DIM + kt * 32 + lg * 8]);
            acc2[f] = MFMA16(a, b, acc2[f]);
        }
    }
#pragma unroll
    for (int r = 0; r < 4; ++r) {
        const int er = e0 + wr * 16 + lg * 4 + r;
        const size_t rr = HTR ? (size_t)e1map[er] : (size_t)er;
#pragma unroll
        for (int f = 0; f < 4; ++f) {
            const int col = wc * 64 + f * 16 + l16;
            t_out[rr * DIM + col] = acc2[f][r] + b2[col] + t_resid[rr * DIM + col];
        }
    }
}

// ---------------------------------------------------------------------------
// EQFF via MFMA, in-place on h2 (fp32), staged from bf16 shadow.
__global__ __launch_bounds__(256) void k_eqff(
    const u16* __restrict__ hb,
    const u16* __restrict__ Wf1T, const float* __restrict__ bf1,
    const u16* __restrict__ Wf2T, const float* __restrict__ bf2,
    float* h_io)
{
    __shared__ __align__(16) u16 xs[32 * 136];
    __shared__ __align__(16) u16 hs[32 * 264];   // hidden [32][256] pad->264
    const int t = threadIdx.x;
    const size_t r0 = (size_t)blockIdx.x * 32;
#pragma unroll
    for (int i = 0; i < 4; ++i) {
        int idx = t + i * 256;
        int row = idx >> 5, c4 = (idx & 31) * 4;
        *reinterpret_cast<us4*>(&xs[row * 136 + c4]) =
            *reinterpret_cast<const us4*>(&hb[(r0 + row) * DIM + c4]);
    }
    __syncthreads();
    const int lane = t & 63, w = t >> 6;
    const int wr = w & 1, wc = w >> 1;
    const int l16 = lane & 15, lg = lane >> 4;
    const int arow = wr * 16 + l16;
    bf16x8 a[4];
#pragma unroll
    for (int kt = 0; kt < 4; ++kt)
        a[kt] = *reinterpret_cast<const bf16x8*>(&xs[arow * 136 + kt * 32 + lg * 8]);

    f32x4 acc1[8];
#pragma unroll
    for (int f = 0; f < 8; ++f) acc1[f] = (f32x4){0.f, 0.f, 0.f, 0.f};
#pragma unroll
    for (int f = 0; f < 8; ++f) {
        const int col = wc * 128 + f * 16 + l16;      // 0..255
#pragma unroll
        for (int kt = 0; kt < 4; ++kt) {
            bf16x8 b = *reinterpret_cast<const bf16x8*>(
                &Wf1T[(size_t)col * DIM + kt * 32 + lg * 8]);
            acc1[f] = MFMA16(a[kt], b, acc1[f]);
        }
    }
#pragma unroll
    for (int f = 0; f < 8; ++f) {
        const int col = wc * 128 + f * 16 + l16;
        const float bb = bf1[col];
#pragma unroll
        for (int r = 0; r < 4; ++r) {
            float x = acc1[f][r] + bb;
            x = x / (1.0f + __expf(-x));
            hs[(wr * 16 + lg * 4 + r) * 264 + col] = f2b(x);
        }
    }
    __syncthreads();

    f32x4 acc2[4]; ZACC4(acc2);
#pragma unroll
    for (int kt = 0; kt < 8; ++kt) {
        bf16x8 a2 = *reinterpret_cast<const bf16x8*>(&hs[arow * 264 + kt * 32 + lg * 8]);
#pragma unroll
        for (int f = 0; f < 4; ++f) {
            const int col = wc * 64 + f * 16 + l16;
            bf16x8 b = *reinterpret_cast<const bf16x8*>(
                &Wf2T[(size_t)col * 256 + kt * 32 + lg * 8]);
            acc2[f] = MFMA16(a2, b, acc2[f]);
        }
    }
#pragma unroll
    for (int f = 0; f < 4; ++f) {
        const int col = wc * 64 + f * 16 + l16;
        const float bb = bf2[col];
#pragma unroll
        for (int r = 0; r < 4; ++r) {
            const size_t row = r0 + wr * 16 + lg * 4 + r;
            h_io[row * DIM + col] = acc2[f][r] + bb + h_io[row * DIM + col];
        }
    }
}

// ---------------------------------------------------------------------------
extern "C" void kernel_launch(void* const* d_in, const int* in_sizes, int n_in,
                              void* d_out, int out_size, void* d_ws, size_t ws_size,
                              hipStream_t stream)
{
    (void)in_sizes; (void)n_in; (void)out_size; (void)ws_size;

    const float* h    = (const float*)d_in[0];
    const float* t_e2 = (const float*)d_in[1];
    const int* ei1    = (const int*)d_in[2];
    const int* ei2    = (const int*)d_in[3];
    const int* e1map  = (const int*)d_in[4];
    const float* Wq = (const float*)d_in[5];  const float* bq = (const float*)d_in[6];
    const float* Wk = (const float*)d_in[7];  const float* bk = (const float*)d_in[8];
    const float* Wv = (const float*)d_in[9];  const float* bv = (const float*)d_in[10];
    const float* Wg = (const float*)d_in[11]; const float* bg = (const float*)d_in[12];
    const float* Wo = (const float*)d_in[13]; const float* bo = (const float*)d_in[14];
    const float* We1= (const float*)d_in[15]; const float* be1= (const float*)d_in[16];
    const float* We2= (const float*)d_in[17]; const float* be2= (const float*)d_in[18];
    const float* Wh1= (const float*)d_in[19]; const float* bh1= (const float*)d_in[20];
    const float* Wh2= (const float*)d_in[21]; const float* bh2= (const float*)d_in[22];
    const float* Wf1= (const float*)d_in[23]; const float* bf1= (const float*)d_in[24];
    const float* Wf2= (const float*)d_in[25]; const float* bf2= (const float*)d_in[26];

    const size_t nd = (size_t)NND * DIM;
    float* ws   = (float*)d_ws;
    float* Hq   = ws;
    float* Hk   = Hq + nd;
    float* Hv   = Hk + nd;
    float* hu   = Hv + nd;
    float* P    = hu + nd;
    int*   gmax = (int*)(P + (size_t)E2N * NH);
    float* gsum = (float*)(gmax + NH);
    u16*   wb   = (u16*)(gsum + NH + 8);          // 16B-aligned weight region

    u16* WqT  = wb;            // 128x128
    u16* WkT  = WqT  + 16384;
    u16* WvT  = WkT  + 16384;
    u16* WoT  = WvT  + 16384;
    u16* We1T = WoT  + 16384;  // 128x384
    u16* We2T = We1T + 49152;  // 128x128
    u16* Wh1T = We2T + 16384;  // 128x384
    u16* Wh2T = Wh1T + 49152;  // 128x128
    u16* Wf1T = Wh2T + 16384;  // 256x128
    u16* Wf2T = Wf1T + 32768;  // 128x256

    u16* h2b = (u16*)Hq;       // bf16 shadow of h2; Hq dead after k_logits

    float* h2    = (float*)d_out;                 // [N, D]
    float* t_out = h2 + nd;                       // [E2, D]

    // weight prep (bf16 transposed)
    k_wprep<<< 64, 256, 0, stream>>>(Wq,  WqT,  DIM, DIM);
    k_wprep<<< 64, 256, 0, stream>>>(Wk,  WkT,  DIM, DIM);
    k_wprep<<< 64, 256, 0, stream>>>(Wv,  WvT,  DIM, DIM);
    k_wprep<<< 64, 256, 0, stream>>>(Wo,  WoT,  DIM, DIM);
    k_wprep<<<192, 256, 0, stream>>>(We1, We1T, 3 * DIM, DIM);
    k_wprep<<< 64, 256, 0, stream>>>(We2, We2T, DIM, DIM);
    k_wprep<<<192, 256, 0, stream>>>(Wh1, Wh1T, 3 * DIM, DIM);
    k_wprep<<< 64, 256, 0, stream>>>(Wh2, Wh2T, DIM, DIM);
    k_wprep<<<128, 256, 0, stream>>>(Wf1, Wf1T, DIM, 2 * DIM);
    k_wprep<<<128, 256, 0, stream>>>(Wf2, Wf2T, 2 * DIM, DIM);

    hipMemsetAsync(hu, 0, nd * sizeof(float), stream);
    k_init<<<1, 64, 0, stream>>>(gmax, gsum);

    k_proj<<<NND / 32, 256, 0, stream>>>(h, WqT, bq, WkT, bk, WvT, bv, Hq, Hk, Hv);
    k_logits<<<(E2N * NH) / 256, 256, 0, stream>>>(Hq, Hk, t_e2, Wg, bg, ei2, P, gmax);
    k_sumexp<<<(E2N * NH) / 256, 256, 0, stream>>>(P, gmax, gsum);
    k_scatter<<<4096, 256, 0, stream>>>(P, gsum, Hv, ei2, hu);
    k_hout<<<NND / 32, 256, 0, stream>>>(hu, h, WoT, bo, h2, h2b);

    k_edge_mlp<false><<<E2N / 32, 256, 0, stream>>>(
        h2b, t_e2, ei2, E2N, nullptr, We1T, be1, We2T, be2, t_out);
    k_edge_mlp<true><<<E1N / 32, 256, 0, stream>>>(
        h2b, t_out, ei1, E1N, e1map, Wh1T, bh1, Wh2T, bh2, t_out);
    k_eqff<<<NND / 32, 256, 0, stream>>>(h2b, Wf1T, bf1, Wf2T, bf2, h2);
}